// Round 2
// baseline (375.740 us; speedup 1.0000x reference)
//
#include <hip/hip_runtime.h>

typedef unsigned int u32;
typedef unsigned short u16;
typedef __bf16 bf16_t;
typedef float f32x4 __attribute__((ext_vector_type(4)));
typedef bf16_t bfrag __attribute__((ext_vector_type(8)));
typedef u16 u16x8 __attribute__((ext_vector_type(8)));

#define WAIT_VMCNT(n) asm volatile("s_waitcnt vmcnt(" #n ")" ::: "memory")

// ---------- helpers ----------
__device__ inline u16 f2bf(float f) {
    union { float f; u32 u; } v; v.f = f;
    u32 r = v.u + 0x7fffu + ((v.u >> 16) & 1u);   // RNE
    return (u16)(r >> 16);
}
__device__ inline float bf2f(u16 h) {
    union { u32 u; float f; } v; v.u = ((u32)h) << 16; return v.f;
}

__device__ inline f32x4 mfma16(bfrag a, bfrag b, f32x4 c) {
    return __builtin_amdgcn_mfma_f32_16x16x32_bf16(a, b, c, 0, 0, 0);
}

__device__ inline void gload_lds16(const void* g, void* l) {
    __builtin_amdgcn_global_load_lds((const __attribute__((address_space(1))) u32*)g,
                                     (__attribute__((address_space(3))) u32*)l, 16, 0, 0);
}

__device__ inline float redmax16(float v) {
    #pragma unroll
    for (int m = 1; m < 16; m <<= 1) v = fmaxf(v, __shfl_xor(v, m));
    return v;
}
__device__ inline float redsum16(float v) {
    #pragma unroll
    for (int m = 1; m < 16; m <<= 1) v += __shfl_xor(v, m);
    return v;
}

// ---------- sizes (fixed problem) ----------
// B=128 T=256 C=384 H=6 D=64; tokens M=32768
#define NTOK 32768
#define QKV_ELEMS 12582912   // 128*6*256*64

// ---------- weight prep: transpose + fp32->bf16 ----------
__global__ __launch_bounds__(256) void prep_weights(
    const float* __restrict__ Wq, const float* __restrict__ Wk,
    const float* __restrict__ Wv, const float* __restrict__ Wo,
    const float* __restrict__ W1, const float* __restrict__ W2,
    u16* __restrict__ wqkvT, u16* __restrict__ woT,
    u16* __restrict__ w1T, u16* __restrict__ w2T)
{
    const int total = 442368 + 147456 + 589824 + 589824;
    int stride = gridDim.x * 256;
    for (int i = blockIdx.x * 256 + threadIdx.x; i < total; i += stride) {
        if (i < 442368) {                       // wqkvT [1152][384]
            int n = i / 384, c = i - n * 384;
            int m2 = n / 384;                   // 0=q 1=k 2=v
            int rem = n - m2 * 384;
            int hh = rem >> 6, d = rem & 63;
            const float* W = (m2 == 0) ? Wq : ((m2 == 1) ? Wk : Wv);
            wqkvT[i] = f2bf(W[((size_t)hh * 384 + c) * 64 + d]);
        } else if (i < 442368 + 147456) {       // woT [384][384]
            int j = i - 442368;
            int n = j / 384, c = j - n * 384;
            woT[j] = f2bf(Wo[(size_t)c * 384 + n]);
        } else if (i < 442368 + 147456 + 589824) { // w1T [1536][384]
            int j = i - 442368 - 147456;
            int n = j / 384, c = j - n * 384;
            w1T[j] = f2bf(W1[(size_t)c * 1536 + n]);
        } else {                                 // w2T [384][1536]
            int j = i - 442368 - 147456 - 589824;
            int n = j / 1536, c = j - n * 1536;
            w2T[j] = f2bf(W2[(size_t)c * 384 + n]);
        }
    }
}

// ---------- layernorm fp32-in ----------
__global__ __launch_bounds__(256) void ln_f32(
    const float* __restrict__ x, const float* __restrict__ g,
    const float* __restrict__ b, u16* __restrict__ out)
{
    const int row = blockIdx.x * 4 + (threadIdx.x >> 6);
    const int lane = threadIdx.x & 63;
    const float2* xr = (const float2*)(x + (size_t)row * 384);
    float2 v[3];
    float s = 0.f, s2 = 0.f;
    #pragma unroll
    for (int i = 0; i < 3; i++) {
        v[i] = xr[lane + i * 64];
        s += v[i].x + v[i].y; s2 += v[i].x * v[i].x + v[i].y * v[i].y;
    }
    #pragma unroll
    for (int m = 1; m < 64; m <<= 1) { s += __shfl_xor(s, m); s2 += __shfl_xor(s2, m); }
    float mean = s * (1.f / 384.f);
    float rstd = rsqrtf(s2 * (1.f / 384.f) - mean * mean + 1e-5f);
    u32* op = (u32*)(out + (size_t)row * 384);
    #pragma unroll
    for (int i = 0; i < 3; i++) {
        int c = (lane + i * 64) * 2;
        u32 lo = f2bf((v[i].x - mean) * rstd * g[c] + b[c]);
        u32 hi = f2bf((v[i].y - mean) * rstd * g[c + 1] + b[c + 1]);
        op[lane + i * 64] = lo | (hi << 16);
    }
}

// ---------- layernorm bf16-in ----------
__global__ __launch_bounds__(256) void ln_bf16(
    const u16* __restrict__ x, const float* __restrict__ g,
    const float* __restrict__ b, u16* __restrict__ out)
{
    const int row = blockIdx.x * 4 + (threadIdx.x >> 6);
    const int lane = threadIdx.x & 63;
    const u32* xr = (const u32*)(x + (size_t)row * 384);
    float vx[3], vy[3];
    float s = 0.f, s2 = 0.f;
    #pragma unroll
    for (int i = 0; i < 3; i++) {
        u32 w = xr[lane + i * 64];
        vx[i] = bf2f((u16)(w & 0xffffu));
        vy[i] = bf2f((u16)(w >> 16));
        s += vx[i] + vy[i]; s2 += vx[i] * vx[i] + vy[i] * vy[i];
    }
    #pragma unroll
    for (int m = 1; m < 64; m <<= 1) { s += __shfl_xor(s, m); s2 += __shfl_xor(s2, m); }
    float mean = s * (1.f / 384.f);
    float rstd = rsqrtf(s2 * (1.f / 384.f) - mean * mean + 1e-5f);
    u32* op = (u32*)(out + (size_t)row * 384);
    #pragma unroll
    for (int i = 0; i < 3; i++) {
        int c = (lane + i * 64) * 2;
        u32 lo = f2bf((vx[i] - mean) * rstd * g[c] + b[c]);
        u32 hi = f2bf((vy[i] - mean) * rstd * g[c + 1] + b[c + 1]);
        op[lane + i * 64] = lo | (hi << 16);
    }
}

// ---------- flat GEMM: A[M,K] x Bt[N,K] -> out ----------
// A staged in LDS (double-buffered, swizzled, global_load_lds 16B).
// B fragments loaded straight from global (weights are L2-resident).
// BM=128 fixed; BN = WN*64; NW waves as 2 x WN grid of 64x64 wave tiles.
// EPI 0: qkv scatter (bf16, q scaled)  EPI 1: bf16 out = f32resid + bias + acc
// EPI 2: bf16 out = relu(acc + bias)   EPI 3: f32 out = bf16resid + bias + acc
template<int EPI, int NW, int WN, int BN>
__global__ __launch_bounds__(NW * 64) void gemm_flat(
    const u16* __restrict__ A, const u16* __restrict__ Bt,
    const float* __restrict__ bias, const void* __restrict__ resid,
    void* __restrict__ outp, int M, int N, int K)
{
    __shared__ __align__(16) u16 As[2][128 * 64];
    const int tid = threadIdx.x, wave = tid >> 6, lane = tid & 63;
    const int nbn = N / BN;
    const int nwg = gridDim.x;
    const int bid = blockIdx.x;
    const int wg = (bid & 7) * (nwg >> 3) + (bid >> 3);   // XCD-chunked swizzle
    const int bm = wg / nbn, bn = wg - bm * nbn;
    const int rowA0 = bm << 7;
    const int wm = wave / WN, wn = wave - wm * WN;
    const int colB0 = bn * BN + wn * 64;
    const int lr = lane >> 3, lc = lane & 7;
    f32x4 acc[4][4] = {};

    // prologue: stage K-step 0 into buffer 0
    #pragma unroll
    for (int idx = wave; idx < 16; idx += NW) {
        const int r = idx * 8 + lr;
        gload_lds16(A + (size_t)(rowA0 + r) * K + ((lc ^ (r & 7)) << 3), &As[0][idx * 512]);
    }
    WAIT_VMCNT(0);
    __builtin_amdgcn_s_barrier();

    const int NT = K >> 6;
    const u16* Brow[4];
    #pragma unroll
    for (int nt = 0; nt < 4; nt++)
        Brow[nt] = Bt + (size_t)(colB0 + nt * 16 + (lane & 15)) * K + ((lane >> 4) << 3);

    int cur = 0;
    for (int t = 0; t < NT; ++t) {
        const int ko = t << 6;
        // B fragments straight from global (L2)
        bfrag bf[2][4];
        #pragma unroll
        for (int kk = 0; kk < 2; kk++)
            #pragma unroll
            for (int nt = 0; nt < 4; nt++)
                bf[kk][nt] = *(const bfrag*)(Brow[nt] + ko + kk * 32);
        // prefetch next A tile into the other buffer
        if (t + 1 < NT) {
            #pragma unroll
            for (int idx = wave; idx < 16; idx += NW) {
                const int r = idx * 8 + lr;
                gload_lds16(A + (size_t)(rowA0 + r) * K + (ko + 64) + ((lc ^ (r & 7)) << 3),
                            &As[cur ^ 1][idx * 512]);
            }
            if constexpr (NW == 4) { WAIT_VMCNT(12); }        // 8 B + 4 cur-stage in flight
            else { if (wave < 16 - NW) { WAIT_VMCNT(10); } else { WAIT_VMCNT(9); } }
        } else {
            WAIT_VMCNT(8);                                     // only 8 B loads in flight
        }
        __builtin_amdgcn_s_barrier();
        const char* Ab = (const char*)&As[cur][0];
        #pragma unroll
        for (int kk = 0; kk < 2; kk++) {
            bfrag af[4];
            #pragma unroll
            for (int mt = 0; mt < 4; mt++) {
                const int row = wm * 64 + mt * 16 + (lane & 15);
                af[mt] = *(const bfrag*)(Ab + row * 128 + (((kk * 4 + (lane >> 4)) ^ (row & 7)) << 4));
            }
            #pragma unroll
            for (int mt = 0; mt < 4; mt++)
                #pragma unroll
                for (int nt = 0; nt < 4; nt++)
                    acc[mt][nt] = mfma16(af[mt], bf[kk][nt], acc[mt][nt]);
        }
        __builtin_amdgcn_s_barrier();
        cur ^= 1;
    }

    #pragma unroll
    for (int mt = 0; mt < 4; mt++) {
        #pragma unroll
        for (int nt = 0; nt < 4; nt++) {
            #pragma unroll
            for (int r2 = 0; r2 < 4; r2++) {
                const int gr = rowA0 + wm * 64 + mt * 16 + ((lane >> 4) << 2) + r2;
                const int gc = colB0 + nt * 16 + (lane & 15);
                float v = acc[mt][nt][r2];
                if constexpr (EPI == 0) {
                    int m2 = gc / 384;
                    int rem = gc - m2 * 384;
                    int hh = rem >> 6, d = rem & 63;
                    if (m2 == 0) v *= 0.125f;  // q * headsize^-0.5
                    int bb = gr >> 8, t2 = gr & 255;
                    ((u16*)outp)[(size_t)m2 * QKV_ELEMS +
                                 ((size_t)((bb * 6 + hh) * 256 + t2) << 6) + d] = f2bf(v);
                } else if constexpr (EPI == 1) {
                    ((u16*)outp)[(size_t)gr * N + gc] =
                        f2bf(((const float*)resid)[(size_t)gr * N + gc] + bias[gc] + v);
                } else if constexpr (EPI == 2) {
                    float t2 = v + bias[gc];
                    ((u16*)outp)[(size_t)gr * N + gc] = f2bf(t2 > 0.f ? t2 : 0.f);
                } else {
                    ((float*)outp)[(size_t)gr * N + gc] =
                        bf2f(((const u16*)resid)[(size_t)gr * N + gc]) + bias[gc] + v;
                }
            }
        }
    }
}

// ---------- attention: one block per (b,h), 8 waves ----------
__global__ __launch_bounds__(512) void attn_kernel(
    const u16* __restrict__ q, const u16* __restrict__ k, const u16* __restrict__ v,
    u16* __restrict__ outp)
{
    __shared__ __align__(16) u16 Ks[256 * 64];
    __shared__ __align__(16) u16 Vt[64 * 256];
    __shared__ __align__(16) u16 Ps[8 * 512];   // per-wave P chunk [16 q][32 key]
    const int bh = blockIdx.x;
    const int tid = threadIdx.x, wave = tid >> 6, lane = tid & 63;
    const u16* qb = q + (size_t)bh * 16384;
    const u16* kb = k + (size_t)bh * 16384;
    const u16* vb = v + (size_t)bh * 16384;

    #pragma unroll
    for (int p = 0; p < 4; p++) {
        const int idx = p * 8 + wave;
        const int r = idx * 8 + (lane >> 3);
        const int csrc = (((lane & 7) ^ (r & 7)) << 3);
        gload_lds16(kb + (size_t)r * 64 + csrc, &Ks[idx * 512]);
    }
    #pragma unroll
    for (int p = 0; p < 4; p++) {
        const int e = (p * 512 + tid) * 8;
        const int key = e >> 6, d0 = e & 63;
        u16x8 raw = *(const u16x8*)(vb + (size_t)key * 64 + d0);
        #pragma unroll
        for (int j = 0; j < 8; j++) {
            const int d = d0 + j;
            Vt[d * 256 + (((key >> 3) ^ (d & 7)) << 3) + (key & 7)] = raw[j];
        }
    }
    __syncthreads();

    const int bI = bh / 6, hh = bh - bI * 6;

    #pragma unroll
    for (int t = 0; t < 2; t++) {
        const int qtile = (t == 0) ? wave : (15 - wave);
        const int qrowbase = qtile * 16;
        bfrag qf[2];
        {
            const int r = qrowbase + (lane & 15);
            qf[0] = *(const bfrag*)(qb + (size_t)r * 64 + ((lane >> 4) << 3));
            qf[1] = *(const bfrag*)(qb + (size_t)r * 64 + 32 + ((lane >> 4) << 3));
        }
        f32x4 S[16];
        #pragma unroll
        for (int kt = 0; kt < 16; kt++) {
            if (kt <= qtile) {
                f32x4 s = {0.f, 0.f, 0.f, 0.f};
                const int key = kt * 16 + (lane & 15);
                const char* kbase = (const char*)Ks + key * 128;
                s = mfma16(qf[0], *(const bfrag*)(kbase + ((((lane >> 4)) ^ (key & 7)) << 4)), s);
                s = mfma16(qf[1], *(const bfrag*)(kbase + (((4 + (lane >> 4)) ^ (key & 7)) << 4)), s);
                if (kt == qtile) {
                    const int qit = (lane >> 4) << 2;
                    #pragma unroll
                    for (int r2 = 0; r2 < 4; r2++)
                        if ((lane & 15) > qit + r2) s[r2] = -1e30f;
                }
                S[kt] = s;
            }
        }
        float mx[4] = {-1e30f, -1e30f, -1e30f, -1e30f};
        #pragma unroll
        for (int kt = 0; kt < 16; kt++) if (kt <= qtile)
            #pragma unroll
            for (int r2 = 0; r2 < 4; r2++) mx[r2] = fmaxf(mx[r2], S[kt][r2]);
        #pragma unroll
        for (int r2 = 0; r2 < 4; r2++) mx[r2] = redmax16(mx[r2]);
        float sm[4] = {0.f, 0.f, 0.f, 0.f};
        #pragma unroll
        for (int kt = 0; kt < 16; kt++) if (kt <= qtile)
            #pragma unroll
            for (int r2 = 0; r2 < 4; r2++) {
                float p = __expf(S[kt][r2] - mx[r2]);
                S[kt][r2] = p; sm[r2] += p;
            }
        #pragma unroll
        for (int r2 = 0; r2 < 4; r2++) sm[r2] = redsum16(sm[r2]);

        f32x4 O[4] = {};
        u16* Pw = &Ps[wave * 512];
        const int nch = (qtile + 2) >> 1;
        #pragma unroll
        for (int ch = 0; ch < 8; ch++) {
            if (ch < nch) {
                #pragma unroll
                for (int ktl = 0; ktl < 2; ktl++) {
                    const int kt = ch * 2 + ktl;
                    const int keyl = ktl * 16 + (lane & 15);
                    const int cidx = keyl >> 3;
                    #pragma unroll
                    for (int r2 = 0; r2 < 4; r2++) {
                        const int qq = ((lane >> 4) << 2) + r2;
                        float pv = (kt <= qtile) ? S[kt][r2] : 0.f;
                        Pw[qq * 32 + ((cidx ^ (qq & 3)) << 3) + (keyl & 7)] = f2bf(pv);
                    }
                }
                const int qq = lane & 15;
                bfrag pa = *(const bfrag*)(Pw + qq * 32 + (((lane >> 4) ^ (qq & 3)) << 3));
                #pragma unroll
                for (int dt = 0; dt < 4; dt++) {
                    const int d = dt * 16 + (lane & 15);
                    const int cc = ch * 4 + (lane >> 4);
                    bfrag vf = *(const bfrag*)((const char*)Vt + d * 512 + ((cc ^ (d & 7)) << 4));
                    O[dt] = mfma16(pa, vf, O[dt]);
                }
            }
        }
        #pragma unroll
        for (int dt = 0; dt < 4; dt++) {
            #pragma unroll
            for (int r2 = 0; r2 < 4; r2++) {
                const int qg = qrowbase + ((lane >> 4) << 2) + r2;
                const float val = O[dt][r2] / sm[r2];
                outp[(size_t)(bI * 256 + qg) * 384 + hh * 64 + dt * 16 + (lane & 15)] = f2bf(val);
            }
        }
    }
}

// ---------- launch ----------
extern "C" void kernel_launch(void* const* d_in, const int* in_sizes, int n_in,
                              void* d_out, int out_size, void* d_ws, size_t ws_size,
                              hipStream_t stream)
{
    const float* x    = (const float*)d_in[0];
    const float* ln1g = (const float*)d_in[1];
    const float* ln1b = (const float*)d_in[2];
    const float* Wq   = (const float*)d_in[3];
    const float* Wk   = (const float*)d_in[4];
    const float* Wv   = (const float*)d_in[5];
    const float* Wo   = (const float*)d_in[6];
    const float* bo   = (const float*)d_in[7];
    const float* ln2g = (const float*)d_in[8];
    const float* ln2b = (const float*)d_in[9];
    const float* W1   = (const float*)d_in[10];
    const float* b1   = (const float*)d_in[11];
    const float* W2   = (const float*)d_in[12];
    const float* b2   = (const float*)d_in[13];

    if (ws_size < 230031360u) return;

    char* ws = (char*)d_ws;
    u16*   wqkvT = (u16*)(ws + 0);
    u16*   woT   = (u16*)(ws + 884736);
    u16*   w1T   = (u16*)(ws + 1179648);
    u16*   w2T   = (u16*)(ws + 2359296);
    u16*   hbuf  = (u16*)(ws + 3538944);    // LN1 out, later attn out
    u16*   qbuf  = (u16*)(ws + 28704768);   // q, later h2 (LN2 out)
    u16*   kbuf  = (u16*)(ws + 53870592);
    u16*   vbuf  = (u16*)(ws + 79036416);
    u16*   x2h   = (u16*)(ws + 104202240);  // bf16 residual stream
    u16*   mid   = (u16*)(ws + 129368064);  // FFN hidden (bf16)
    float* out   = (float*)d_out;

    prep_weights<<<1024, 256, 0, stream>>>(Wq, Wk, Wv, Wo, W1, W2, wqkvT, woT, w1T, w2T);
    ln_f32<<<8192, 256, 0, stream>>>(x, ln1g, ln1b, hbuf);
    gemm_flat<0, 4, 2, 128><<<2304, 256, 0, stream>>>(hbuf, wqkvT, nullptr, nullptr, qbuf,
                                                      NTOK, 1152, 384);
    attn_kernel<<<768, 512, 0, stream>>>(qbuf, kbuf, vbuf, hbuf);
    gemm_flat<1, 4, 2, 128><<<768, 256, 0, stream>>>(hbuf, woT, bo, x, x2h, NTOK, 384, 384);
    ln_bf16<<<8192, 256, 0, stream>>>(x2h, ln2g, ln2b, qbuf);
    gemm_flat<2, 4, 2, 128><<<3072, 256, 0, stream>>>(qbuf, w1T, b1, nullptr, mid,
                                                      NTOK, 1536, 384);
    gemm_flat<3, 12, 6, 384><<<256, 768, 0, stream>>>(mid, w2T, b2, x2h, out,
                                                      NTOK, 384, 1536);
}

// Round 3
// 260.341 us; speedup vs baseline: 1.4433x; 1.4433x over previous
//
#include <hip/hip_runtime.h>

typedef unsigned int u32;
typedef unsigned short u16;
typedef __bf16 bf16_t;
typedef float f32x4 __attribute__((ext_vector_type(4)));
typedef bf16_t bfrag __attribute__((ext_vector_type(8)));
typedef u16 u16x8 __attribute__((ext_vector_type(8)));

#define WAIT_VMCNT(n) asm volatile("s_waitcnt vmcnt(" #n ")" ::: "memory")

// ---------- helpers ----------
__device__ inline u16 f2bf(float f) {
    union { float f; u32 u; } v; v.f = f;
    u32 r = v.u + 0x7fffu + ((v.u >> 16) & 1u);   // RNE
    return (u16)(r >> 16);
}
__device__ inline float bf2f(u16 h) {
    union { u32 u; float f; } v; v.u = ((u32)h) << 16; return v.f;
}

__device__ inline f32x4 mfma16(bfrag a, bfrag b, f32x4 c) {
    return __builtin_amdgcn_mfma_f32_16x16x32_bf16(a, b, c, 0, 0, 0);
}

__device__ inline void gload_lds16(const void* g, void* l) {
    __builtin_amdgcn_global_load_lds((const __attribute__((address_space(1))) u32*)g,
                                     (__attribute__((address_space(3))) u32*)l, 16, 0, 0);
}

__device__ inline float redmax16(float v) {
    #pragma unroll
    for (int m = 1; m < 16; m <<= 1) v = fmaxf(v, __shfl_xor(v, m));
    return v;
}
__device__ inline float redsum16(float v) {
    #pragma unroll
    for (int m = 1; m < 16; m <<= 1) v += __shfl_xor(v, m);
    return v;
}

// ---------- sizes (fixed problem) ----------
// B=128 T=256 C=384 H=6 D=64; tokens M=32768
#define NTOK 32768
#define QKV_ELEMS 12582912   // 128*6*256*64

// ---------- weight prep: tiled 64x64 transpose fp32->bf16 ----------
// 432 tiles: Wo 36, W1 144, W2 144, Wq/Wk/Wv 108.
__global__ __launch_bounds__(256) void prep_weights(
    const float* __restrict__ Wq, const float* __restrict__ Wk,
    const float* __restrict__ Wv, const float* __restrict__ Wo,
    const float* __restrict__ W1, const float* __restrict__ W2,
    u16* __restrict__ wqkvT, u16* __restrict__ woT,
    u16* __restrict__ w1T, u16* __restrict__ w2T)
{
    __shared__ float tile[64][65];
    const int b = blockIdx.x;
    const float* src; u16* dst;
    int sr0, sc0, srs, dr0, dc0, drs;
    if (b < 36) {                       // Wo [384][384] -> woT [384][384]
        int i = b / 6, j = b - i * 6;
        src = Wo;  srs = 384;  sr0 = i * 64; sc0 = j * 64;
        dst = woT; drs = 384;  dr0 = j * 64; dc0 = i * 64;
    } else if (b < 180) {               // W1 [384][1536] -> w1T [1536][384]
        int t = b - 36; int i = t / 24, j = t - i * 24;
        src = W1;  srs = 1536; sr0 = i * 64; sc0 = j * 64;
        dst = w1T; drs = 384;  dr0 = j * 64; dc0 = i * 64;
    } else if (b < 324) {               // W2 [1536][384] -> w2T [384][1536]
        int t = b - 180; int i = t / 6, j = t - i * 6;
        src = W2;  srs = 384;  sr0 = i * 64; sc0 = j * 64;
        dst = w2T; drs = 1536; dr0 = j * 64; dc0 = i * 64;
    } else {                            // W{q,k,v} [6][384][64] -> wqkvT [1152][384]
        int t = b - 324;
        int m2 = t / 36; t -= m2 * 36;
        int h = t / 6, tt = t - h * 6;
        src = (m2 == 0) ? Wq : ((m2 == 1) ? Wk : Wv);
        srs = 64;  sr0 = h * 384 + tt * 64; sc0 = 0;
        dst = wqkvT; drs = 384; dr0 = m2 * 384 + h * 64; dc0 = tt * 64;
    }
    const int lane = threadIdx.x & 63, grp = threadIdx.x >> 6;
    #pragma unroll
    for (int i = 0; i < 16; i++) {
        int r = grp * 16 + i;
        tile[r][lane] = src[(size_t)(sr0 + r) * srs + sc0 + lane];
    }
    __syncthreads();
    #pragma unroll
    for (int i = 0; i < 16; i++) {
        int r = grp * 16 + i;           // dst row offset = src col index
        dst[(size_t)(dr0 + r) * drs + dc0 + lane] = f2bf(tile[lane][r]);
    }
}

// ---------- layernorm fp32-in ----------
__global__ __launch_bounds__(256) void ln_f32(
    const float* __restrict__ x, const float* __restrict__ g,
    const float* __restrict__ b, u16* __restrict__ out)
{
    const int row = blockIdx.x * 4 + (threadIdx.x >> 6);
    const int lane = threadIdx.x & 63;
    const float2* xr = (const float2*)(x + (size_t)row * 384);
    float2 v[3];
    float s = 0.f, s2 = 0.f;
    #pragma unroll
    for (int i = 0; i < 3; i++) {
        v[i] = xr[lane + i * 64];
        s += v[i].x + v[i].y; s2 += v[i].x * v[i].x + v[i].y * v[i].y;
    }
    #pragma unroll
    for (int m = 1; m < 64; m <<= 1) { s += __shfl_xor(s, m); s2 += __shfl_xor(s2, m); }
    float mean = s * (1.f / 384.f);
    float rstd = rsqrtf(s2 * (1.f / 384.f) - mean * mean + 1e-5f);
    u32* op = (u32*)(out + (size_t)row * 384);
    #pragma unroll
    for (int i = 0; i < 3; i++) {
        int c = (lane + i * 64) * 2;
        u32 lo = f2bf((v[i].x - mean) * rstd * g[c] + b[c]);
        u32 hi = f2bf((v[i].y - mean) * rstd * g[c + 1] + b[c + 1]);
        op[lane + i * 64] = lo | (hi << 16);
    }
}

// ---------- layernorm bf16-in ----------
__global__ __launch_bounds__(256) void ln_bf16(
    const u16* __restrict__ x, const float* __restrict__ g,
    const float* __restrict__ b, u16* __restrict__ out)
{
    const int row = blockIdx.x * 4 + (threadIdx.x >> 6);
    const int lane = threadIdx.x & 63;
    const u32* xr = (const u32*)(x + (size_t)row * 384);
    float vx[3], vy[3];
    float s = 0.f, s2 = 0.f;
    #pragma unroll
    for (int i = 0; i < 3; i++) {
        u32 w = xr[lane + i * 64];
        vx[i] = bf2f((u16)(w & 0xffffu));
        vy[i] = bf2f((u16)(w >> 16));
        s += vx[i] + vy[i]; s2 += vx[i] * vx[i] + vy[i] * vy[i];
    }
    #pragma unroll
    for (int m = 1; m < 64; m <<= 1) { s += __shfl_xor(s, m); s2 += __shfl_xor(s2, m); }
    float mean = s * (1.f / 384.f);
    float rstd = rsqrtf(s2 * (1.f / 384.f) - mean * mean + 1e-5f);
    u32* op = (u32*)(out + (size_t)row * 384);
    #pragma unroll
    for (int i = 0; i < 3; i++) {
        int c = (lane + i * 64) * 2;
        u32 lo = f2bf((vx[i] - mean) * rstd * g[c] + b[c]);
        u32 hi = f2bf((vy[i] - mean) * rstd * g[c + 1] + b[c + 1]);
        op[lane + i * 64] = lo | (hi << 16);
    }
}

// ---------- pipelined GEMM: A[M,K] x Bt[N,K], 128x128 tile, BK=64 ----------
// Both operands staged via global_load_lds, double-buffered, counted vmcnt(8).
// 2 barriers/K-step, raw s_barrier (no full drain in the main loop).
// EPI 0: qkv scatter (bf16, q scaled)  EPI 1: bf16 out = f32resid + bias + acc
// EPI 2: bf16 out = relu(acc + bias)   EPI 3: f32 out = bf16resid + bias + acc
template<int EPI, int NT>
__global__ __launch_bounds__(256) void gemm_pipe(
    const u16* __restrict__ A, const u16* __restrict__ Bt,
    const float* __restrict__ bias, const void* __restrict__ resid,
    void* __restrict__ outp, int M, int N)
{
    const int K = NT * 64;
    __shared__ __align__(16) u16 As[2][128 * 64];
    __shared__ __align__(16) u16 Bs[2][128 * 64];
    const int tid = threadIdx.x, wave = tid >> 6, lane = tid & 63;
    const int nbn = N >> 7;
    const int nwg = gridDim.x;
    const int bid = blockIdx.x;
    const int wg = (bid & 7) * (nwg >> 3) + (bid >> 3);   // XCD-chunked swizzle
    const int bm = wg / nbn, bn = wg - bm * nbn;          // bn fastest: A L2 reuse
    const int rowA0 = bm << 7, rowB0 = bn << 7;
    const int wm = (wave >> 1) << 6, wn = (wave & 1) << 6;
    const int lr = lane >> 3, lc = lane & 7;
    f32x4 acc[4][4] = {};

    // per-wave staging: 4 A-chunks + 4 B-chunks of 8 rows each
#define STAGE(buf, ko)                                                              \
    {                                                                               \
        _Pragma("unroll")                                                           \
        for (int p = 0; p < 4; p++) {                                               \
            const int idx = p * 4 + wave;                                           \
            const int r = idx * 8 + lr;                                             \
            const int csrc = ((lc ^ (r & 7)) << 3);                                 \
            gload_lds16(A + (size_t)(rowA0 + r) * K + (ko) + csrc,                  \
                        &As[buf][idx * 512]);                                       \
            gload_lds16(Bt + (size_t)(rowB0 + r) * K + (ko) + csrc,                 \
                        &Bs[buf][idx * 512]);                                       \
        }                                                                           \
    }

    STAGE(0, 0);
    WAIT_VMCNT(0);
    __builtin_amdgcn_s_barrier();

    for (int t = 0; t < NT; ++t) {
        if (t + 1 < NT) {
            STAGE((t + 1) & 1, (t + 1) << 6);
            WAIT_VMCNT(8);                 // drains stage(t); stage(t+1) stays in flight
        } else {
            WAIT_VMCNT(0);
        }
        __builtin_amdgcn_s_barrier();
        const char* Ab = (const char*)&As[t & 1][0];
        const char* Bb = (const char*)&Bs[t & 1][0];
        #pragma unroll
        for (int kk = 0; kk < 2; kk++) {
            bfrag af[4], bfr[4];
            #pragma unroll
            for (int mt = 0; mt < 4; mt++) {
                const int row = wm + mt * 16 + (lane & 15);
                af[mt] = *(const bfrag*)(Ab + row * 128 +
                          (((kk * 4 + (lane >> 4)) ^ (row & 7)) << 4));
            }
            #pragma unroll
            for (int nt = 0; nt < 4; nt++) {
                const int row = wn + nt * 16 + (lane & 15);
                bfr[nt] = *(const bfrag*)(Bb + row * 128 +
                          (((kk * 4 + (lane >> 4)) ^ (row & 7)) << 4));
            }
            #pragma unroll
            for (int mt = 0; mt < 4; mt++)
                #pragma unroll
                for (int nt = 0; nt < 4; nt++)
                    acc[mt][nt] = mfma16(af[mt], bfr[nt], acc[mt][nt]);
        }
        __builtin_amdgcn_s_barrier();      // protect buf (t&1) before overwrite at t+1
    }
#undef STAGE

    #pragma unroll
    for (int mt = 0; mt < 4; mt++) {
        #pragma unroll
        for (int nt = 0; nt < 4; nt++) {
            #pragma unroll
            for (int r2 = 0; r2 < 4; r2++) {
                const int gr = rowA0 + wm + mt * 16 + ((lane >> 4) << 2) + r2;
                const int gc = rowB0 + wn + nt * 16 + (lane & 15);
                float v = acc[mt][nt][r2];
                if constexpr (EPI == 0) {
                    int m2 = gc / 384;
                    int rem = gc - m2 * 384;
                    int hh = rem >> 6, d = rem & 63;
                    if (m2 == 0) v *= 0.125f;  // q * headsize^-0.5
                    int bb = gr >> 8, t2 = gr & 255;
                    ((u16*)outp)[(size_t)m2 * QKV_ELEMS +
                                 ((size_t)((bb * 6 + hh) * 256 + t2) << 6) + d] = f2bf(v);
                } else if constexpr (EPI == 1) {
                    ((u16*)outp)[(size_t)gr * N + gc] =
                        f2bf(((const float*)resid)[(size_t)gr * N + gc] + bias[gc] + v);
                } else if constexpr (EPI == 2) {
                    float t2 = v + bias[gc];
                    ((u16*)outp)[(size_t)gr * N + gc] = f2bf(t2 > 0.f ? t2 : 0.f);
                } else {
                    ((float*)outp)[(size_t)gr * N + gc] =
                        bf2f(((const u16*)resid)[(size_t)gr * N + gc]) + bias[gc] + v;
                }
            }
        }
    }
}

// ---------- attention: one block per (b,h), 8 waves ----------
__global__ __launch_bounds__(512) void attn_kernel(
    const u16* __restrict__ q, const u16* __restrict__ k, const u16* __restrict__ v,
    u16* __restrict__ outp)
{
    __shared__ __align__(16) u16 Ks[256 * 64];
    __shared__ __align__(16) u16 Vt[64 * 256];
    __shared__ __align__(16) u16 Ps[8 * 512];   // per-wave P chunk [16 q][32 key]
    const int bh = blockIdx.x;
    const int tid = threadIdx.x, wave = tid >> 6, lane = tid & 63;
    const u16* qb = q + (size_t)bh * 16384;
    const u16* kb = k + (size_t)bh * 16384;
    const u16* vb = v + (size_t)bh * 16384;

    #pragma unroll
    for (int p = 0; p < 4; p++) {
        const int idx = p * 8 + wave;
        const int r = idx * 8 + (lane >> 3);
        const int csrc = (((lane & 7) ^ (r & 7)) << 3);
        gload_lds16(kb + (size_t)r * 64 + csrc, &Ks[idx * 512]);
    }
    #pragma unroll
    for (int p = 0; p < 4; p++) {
        const int e = (p * 512 + tid) * 8;
        const int key = e >> 6, d0 = e & 63;
        u16x8 raw = *(const u16x8*)(vb + (size_t)key * 64 + d0);
        #pragma unroll
        for (int j = 0; j < 8; j++) {
            const int d = d0 + j;
            Vt[d * 256 + (((key >> 3) ^ (d & 7)) << 3) + (key & 7)] = raw[j];
        }
    }
    __syncthreads();

    const int bI = bh / 6, hh = bh - bI * 6;

    #pragma unroll
    for (int t = 0; t < 2; t++) {
        const int qtile = (t == 0) ? wave : (15 - wave);
        const int qrowbase = qtile * 16;
        bfrag qf[2];
        {
            const int r = qrowbase + (lane & 15);
            qf[0] = *(const bfrag*)(qb + (size_t)r * 64 + ((lane >> 4) << 3));
            qf[1] = *(const bfrag*)(qb + (size_t)r * 64 + 32 + ((lane >> 4) << 3));
        }
        f32x4 S[16];
        #pragma unroll
        for (int kt = 0; kt < 16; kt++) {
            if (kt <= qtile) {
                f32x4 s = {0.f, 0.f, 0.f, 0.f};
                const int key = kt * 16 + (lane & 15);
                const char* kbase = (const char*)Ks + key * 128;
                s = mfma16(qf[0], *(const bfrag*)(kbase + ((((lane >> 4)) ^ (key & 7)) << 4)), s);
                s = mfma16(qf[1], *(const bfrag*)(kbase + (((4 + (lane >> 4)) ^ (key & 7)) << 4)), s);
                if (kt == qtile) {
                    const int qit = (lane >> 4) << 2;
                    #pragma unroll
                    for (int r2 = 0; r2 < 4; r2++)
                        if ((lane & 15) > qit + r2) s[r2] = -1e30f;
                }
                S[kt] = s;
            }
        }
        float mx[4] = {-1e30f, -1e30f, -1e30f, -1e30f};
        #pragma unroll
        for (int kt = 0; kt < 16; kt++) if (kt <= qtile)
            #pragma unroll
            for (int r2 = 0; r2 < 4; r2++) mx[r2] = fmaxf(mx[r2], S[kt][r2]);
        #pragma unroll
        for (int r2 = 0; r2 < 4; r2++) mx[r2] = redmax16(mx[r2]);
        float sm[4] = {0.f, 0.f, 0.f, 0.f};
        #pragma unroll
        for (int kt = 0; kt < 16; kt++) if (kt <= qtile)
            #pragma unroll
            for (int r2 = 0; r2 < 4; r2++) {
                float p = __expf(S[kt][r2] - mx[r2]);
                S[kt][r2] = p; sm[r2] += p;
            }
        #pragma unroll
        for (int r2 = 0; r2 < 4; r2++) sm[r2] = redsum16(sm[r2]);

        f32x4 O[4] = {};
        u16* Pw = &Ps[wave * 512];
        const int nch = (qtile + 2) >> 1;
        #pragma unroll
        for (int ch = 0; ch < 8; ch++) {
            if (ch < nch) {
                #pragma unroll
                for (int ktl = 0; ktl < 2; ktl++) {
                    const int kt = ch * 2 + ktl;
                    const int keyl = ktl * 16 + (lane & 15);
                    const int cidx = keyl >> 3;
                    #pragma unroll
                    for (int r2 = 0; r2 < 4; r2++) {
                        const int qq = ((lane >> 4) << 2) + r2;
                        float pv = (kt <= qtile) ? S[kt][r2] : 0.f;
                        Pw[qq * 32 + ((cidx ^ (qq & 3)) << 3) + (keyl & 7)] = f2bf(pv);
                    }
                }
                const int qq = lane & 15;
                bfrag pa = *(const bfrag*)(Pw + qq * 32 + (((lane >> 4) ^ (qq & 3)) << 3));
                #pragma unroll
                for (int dt = 0; dt < 4; dt++) {
                    const int d = dt * 16 + (lane & 15);
                    const int cc = ch * 4 + (lane >> 4);
                    bfrag vf = *(const bfrag*)((const char*)Vt + d * 512 + ((cc ^ (d & 7)) << 4));
                    O[dt] = mfma16(pa, vf, O[dt]);
                }
            }
        }
        #pragma unroll
        for (int dt = 0; dt < 4; dt++) {
            #pragma unroll
            for (int r2 = 0; r2 < 4; r2++) {
                const int qg = qrowbase + ((lane >> 4) << 2) + r2;
                const float val = O[dt][r2] / sm[r2];
                outp[(size_t)(bI * 256 + qg) * 384 + hh * 64 + dt * 16 + (lane & 15)] = f2bf(val);
            }
        }
    }
}

// ---------- launch ----------
extern "C" void kernel_launch(void* const* d_in, const int* in_sizes, int n_in,
                              void* d_out, int out_size, void* d_ws, size_t ws_size,
                              hipStream_t stream)
{
    const float* x    = (const float*)d_in[0];
    const float* ln1g = (const float*)d_in[1];
    const float* ln1b = (const float*)d_in[2];
    const float* Wq   = (const float*)d_in[3];
    const float* Wk   = (const float*)d_in[4];
    const float* Wv   = (const float*)d_in[5];
    const float* Wo   = (const float*)d_in[6];
    const float* bo   = (const float*)d_in[7];
    const float* ln2g = (const float*)d_in[8];
    const float* ln2b = (const float*)d_in[9];
    const float* W1   = (const float*)d_in[10];
    const float* b1   = (const float*)d_in[11];
    const float* W2   = (const float*)d_in[12];
    const float* b2   = (const float*)d_in[13];

    if (ws_size < 230031360u) return;

    char* ws = (char*)d_ws;
    u16*   wqkvT = (u16*)(ws + 0);
    u16*   woT   = (u16*)(ws + 884736);
    u16*   w1T   = (u16*)(ws + 1179648);
    u16*   w2T   = (u16*)(ws + 2359296);
    u16*   hbuf  = (u16*)(ws + 3538944);    // LN1 out, later attn out
    u16*   qbuf  = (u16*)(ws + 28704768);   // q, later h2 (LN2 out)
    u16*   kbuf  = (u16*)(ws + 53870592);
    u16*   vbuf  = (u16*)(ws + 79036416);
    u16*   x2h   = (u16*)(ws + 104202240);  // bf16 residual stream
    u16*   mid   = (u16*)(ws + 129368064);  // FFN hidden (bf16)
    float* out   = (float*)d_out;

    prep_weights<<<432, 256, 0, stream>>>(Wq, Wk, Wv, Wo, W1, W2, wqkvT, woT, w1T, w2T);
    ln_f32<<<8192, 256, 0, stream>>>(x, ln1g, ln1b, hbuf);
    gemm_pipe<0, 6><<<2304, 256, 0, stream>>>(hbuf, wqkvT, nullptr, nullptr, qbuf,
                                              NTOK, 1152);
    attn_kernel<<<768, 512, 0, stream>>>(qbuf, kbuf, vbuf, hbuf);
    gemm_pipe<1, 6><<<768, 256, 0, stream>>>(hbuf, woT, bo, x, x2h, NTOK, 384);
    ln_bf16<<<8192, 256, 0, stream>>>(x2h, ln2g, ln2b, qbuf);
    gemm_pipe<2, 6><<<3072, 256, 0, stream>>>(qbuf, w1T, b1, nullptr, mid, NTOK, 1536);
    gemm_pipe<3, 24><<<768, 256, 0, stream>>>(mid, w2T, b2, x2h, out, NTOK, 384);
}

// Round 4
// 246.922 us; speedup vs baseline: 1.5217x; 1.0543x over previous
//
#include <hip/hip_runtime.h>

typedef unsigned int u32;
typedef unsigned short u16;
typedef __bf16 bf16_t;
typedef float f32x4 __attribute__((ext_vector_type(4)));
typedef bf16_t bfrag __attribute__((ext_vector_type(8)));
typedef u16 u16x8 __attribute__((ext_vector_type(8)));

#define WAIT_VMCNT(n) asm volatile("s_waitcnt vmcnt(" #n ")" ::: "memory")

// ---------- helpers ----------
__device__ inline u16 f2bf(float f) {
    union { float f; u32 u; } v; v.f = f;
    u32 r = v.u + 0x7fffu + ((v.u >> 16) & 1u);   // RNE
    return (u16)(r >> 16);
}
__device__ inline float bf2f(u16 h) {
    union { u32 u; float f; } v; v.u = ((u32)h) << 16; return v.f;
}

__device__ inline f32x4 mfma16(bfrag a, bfrag b, f32x4 c) {
    return __builtin_amdgcn_mfma_f32_16x16x32_bf16(a, b, c, 0, 0, 0);
}

__device__ inline void gload_lds16(const void* g, void* l) {
    __builtin_amdgcn_global_load_lds((const __attribute__((address_space(1))) u32*)g,
                                     (__attribute__((address_space(3))) u32*)l, 16, 0, 0);
}

__device__ inline float redmax16(float v) {
    #pragma unroll
    for (int m = 1; m < 16; m <<= 1) v = fmaxf(v, __shfl_xor(v, m));
    return v;
}
__device__ inline float redsum16(float v) {
    #pragma unroll
    for (int m = 1; m < 16; m <<= 1) v += __shfl_xor(v, m);
    return v;
}

// ---------- sizes (fixed problem) ----------
// B=128 T=256 C=384 H=6 D=64; tokens M=32768
#define NTOK 32768
#define QKV_ELEMS 12582912   // 128*6*256*64

// ---------- weight prep: tiled 64x64 transpose fp32->bf16 ----------
__global__ __launch_bounds__(256) void prep_weights(
    const float* __restrict__ Wq, const float* __restrict__ Wk,
    const float* __restrict__ Wv, const float* __restrict__ Wo,
    const float* __restrict__ W1, const float* __restrict__ W2,
    u16* __restrict__ wqkvT, u16* __restrict__ woT,
    u16* __restrict__ w1T, u16* __restrict__ w2T)
{
    __shared__ float tile[64][65];
    const int b = blockIdx.x;
    const float* src; u16* dst;
    int sr0, sc0, srs, dr0, dc0, drs;
    if (b < 36) {                       // Wo [384][384] -> woT [384][384]
        int i = b / 6, j = b - i * 6;
        src = Wo;  srs = 384;  sr0 = i * 64; sc0 = j * 64;
        dst = woT; drs = 384;  dr0 = j * 64; dc0 = i * 64;
    } else if (b < 180) {               // W1 [384][1536] -> w1T [1536][384]
        int t = b - 36; int i = t / 24, j = t - i * 24;
        src = W1;  srs = 1536; sr0 = i * 64; sc0 = j * 64;
        dst = w1T; drs = 384;  dr0 = j * 64; dc0 = i * 64;
    } else if (b < 324) {               // W2 [1536][384] -> w2T [384][1536]
        int t = b - 180; int i = t / 6, j = t - i * 6;
        src = W2;  srs = 384;  sr0 = i * 64; sc0 = j * 64;
        dst = w2T; drs = 1536; dr0 = j * 64; dc0 = i * 64;
    } else {                            // W{q,k,v} [6][384][64] -> wqkvT [1152][384]
        int t = b - 324;
        int m2 = t / 36; t -= m2 * 36;
        int h = t / 6, tt = t - h * 6;
        src = (m2 == 0) ? Wq : ((m2 == 1) ? Wk : Wv);
        srs = 64;  sr0 = h * 384 + tt * 64; sc0 = 0;
        dst = wqkvT; drs = 384; dr0 = m2 * 384 + h * 64; dc0 = tt * 64;
    }
    const int lane = threadIdx.x & 63, grp = threadIdx.x >> 6;
    #pragma unroll
    for (int i = 0; i < 16; i++) {
        int r = grp * 16 + i;
        tile[r][lane] = src[(size_t)(sr0 + r) * srs + sc0 + lane];
    }
    __syncthreads();
    #pragma unroll
    for (int i = 0; i < 16; i++) {
        int r = grp * 16 + i;
        dst[(size_t)(dr0 + r) * drs + dc0 + lane] = f2bf(tile[lane][r]);
    }
}

// ---------- layernorm fp32-in ----------
__global__ __launch_bounds__(256) void ln_f32(
    const float* __restrict__ x, const float* __restrict__ g,
    const float* __restrict__ b, u16* __restrict__ out)
{
    const int row = blockIdx.x * 4 + (threadIdx.x >> 6);
    const int lane = threadIdx.x & 63;
    const float2* xr = (const float2*)(x + (size_t)row * 384);
    float2 v[3];
    float s = 0.f, s2 = 0.f;
    #pragma unroll
    for (int i = 0; i < 3; i++) {
        v[i] = xr[lane + i * 64];
        s += v[i].x + v[i].y; s2 += v[i].x * v[i].x + v[i].y * v[i].y;
    }
    #pragma unroll
    for (int m = 1; m < 64; m <<= 1) { s += __shfl_xor(s, m); s2 += __shfl_xor(s2, m); }
    float mean = s * (1.f / 384.f);
    float rstd = rsqrtf(s2 * (1.f / 384.f) - mean * mean + 1e-5f);
    u32* op = (u32*)(out + (size_t)row * 384);
    #pragma unroll
    for (int i = 0; i < 3; i++) {
        int c = (lane + i * 64) * 2;
        u32 lo = f2bf((v[i].x - mean) * rstd * g[c] + b[c]);
        u32 hi = f2bf((v[i].y - mean) * rstd * g[c + 1] + b[c + 1]);
        op[lane + i * 64] = lo | (hi << 16);
    }
}

// ---------- layernorm bf16-in ----------
__global__ __launch_bounds__(256) void ln_bf16(
    const u16* __restrict__ x, const float* __restrict__ g,
    const float* __restrict__ b, u16* __restrict__ out)
{
    const int row = blockIdx.x * 4 + (threadIdx.x >> 6);
    const int lane = threadIdx.x & 63;
    const u32* xr = (const u32*)(x + (size_t)row * 384);
    float vx[3], vy[3];
    float s = 0.f, s2 = 0.f;
    #pragma unroll
    for (int i = 0; i < 3; i++) {
        u32 w = xr[lane + i * 64];
        vx[i] = bf2f((u16)(w & 0xffffu));
        vy[i] = bf2f((u16)(w >> 16));
        s += vx[i] + vy[i]; s2 += vx[i] * vx[i] + vy[i] * vy[i];
    }
    #pragma unroll
    for (int m = 1; m < 64; m <<= 1) { s += __shfl_xor(s, m); s2 += __shfl_xor(s2, m); }
    float mean = s * (1.f / 384.f);
    float rstd = rsqrtf(s2 * (1.f / 384.f) - mean * mean + 1e-5f);
    u32* op = (u32*)(out + (size_t)row * 384);
    #pragma unroll
    for (int i = 0; i < 3; i++) {
        int c = (lane + i * 64) * 2;
        u32 lo = f2bf((vx[i] - mean) * rstd * g[c] + b[c]);
        u32 hi = f2bf((vy[i] - mean) * rstd * g[c + 1] + b[c + 1]);
        op[lane + i * 64] = lo | (hi << 16);
    }
}

// ---------- pipelined GEMM: A[M,K] x Bt[N,K], 128x128 tile, BK=64, 8 waves ----------
// Wave grid 4x2, wave tile 32x64 (acc[2][4] = 32 VGPR) -> 16 waves/CU resident.
// Double-buffered LDS, counted vmcnt(4), raw s_barrier.
// EPI 0: qkv scatter (bf16, q scaled)  EPI 1: bf16 out = f32resid + bias + acc
// EPI 2: bf16 out = relu(acc + bias)   EPI 3: f32 out = bf16resid + bias + acc
template<int EPI, int NT>
__global__ __launch_bounds__(512, 4) void gemm_pipe(
    const u16* __restrict__ A, const u16* __restrict__ Bt,
    const float* __restrict__ bias, const void* __restrict__ resid,
    void* __restrict__ outp, int M, int N)
{
    const int K = NT * 64;
    __shared__ __align__(16) u16 As[2][128 * 64];
    __shared__ __align__(16) u16 Bs[2][128 * 64];
    const int tid = threadIdx.x, wave = tid >> 6, lane = tid & 63;
    const int nbn = N >> 7;
    const int nwg = gridDim.x;
    const int bid = blockIdx.x;
    const int wg = (bid & 7) * (nwg >> 3) + (bid >> 3);   // XCD-chunked swizzle
    const int bm = wg / nbn, bn = wg - bm * nbn;          // bn fastest: A L2 reuse
    const int rowA0 = bm << 7, rowB0 = bn << 7;
    const int wm = (wave >> 1) << 5, wn = (wave & 1) << 6;
    const int lr = lane >> 3, lc = lane & 7;
    f32x4 acc[2][4] = {};

    // per-wave staging: 2 A-chunks + 2 B-chunks of 8 rows each (4 loads/wave)
#define STAGE(buf, ko)                                                              \
    {                                                                               \
        _Pragma("unroll")                                                           \
        for (int p = 0; p < 2; p++) {                                               \
            const int idx = p * 8 + wave;                                           \
            const int r = idx * 8 + lr;                                             \
            const int csrc = ((lc ^ (r & 7)) << 3);                                 \
            gload_lds16(A + (size_t)(rowA0 + r) * K + (ko) + csrc,                  \
                        &As[buf][idx * 512]);                                       \
            gload_lds16(Bt + (size_t)(rowB0 + r) * K + (ko) + csrc,                 \
                        &Bs[buf][idx * 512]);                                       \
        }                                                                           \
    }

    STAGE(0, 0);
    WAIT_VMCNT(0);
    __builtin_amdgcn_s_barrier();

    for (int t = 0; t < NT; ++t) {
        if (t + 1 < NT) {
            STAGE((t + 1) & 1, (t + 1) << 6);
            WAIT_VMCNT(4);                 // drains stage(t); stage(t+1) stays in flight
        } else {
            WAIT_VMCNT(0);
        }
        __builtin_amdgcn_s_barrier();
        const char* Ab = (const char*)&As[t & 1][0];
        const char* Bb = (const char*)&Bs[t & 1][0];
        #pragma unroll
        for (int kk = 0; kk < 2; kk++) {
            bfrag af[2], bfr[4];
            #pragma unroll
            for (int mt = 0; mt < 2; mt++) {
                const int row = wm + mt * 16 + (lane & 15);
                af[mt] = *(const bfrag*)(Ab + row * 128 +
                          (((kk * 4 + (lane >> 4)) ^ (row & 7)) << 4));
            }
            #pragma unroll
            for (int nt = 0; nt < 4; nt++) {
                const int row = wn + nt * 16 + (lane & 15);
                bfr[nt] = *(const bfrag*)(Bb + row * 128 +
                          (((kk * 4 + (lane >> 4)) ^ (row & 7)) << 4));
            }
            #pragma unroll
            for (int mt = 0; mt < 2; mt++)
                #pragma unroll
                for (int nt = 0; nt < 4; nt++)
                    acc[mt][nt] = mfma16(af[mt], bfr[nt], acc[mt][nt]);
        }
        __builtin_amdgcn_s_barrier();      // protect buf (t&1) before overwrite at t+1
    }
#undef STAGE

    #pragma unroll
    for (int mt = 0; mt < 2; mt++) {
        #pragma unroll
        for (int nt = 0; nt < 4; nt++) {
            #pragma unroll
            for (int r2 = 0; r2 < 4; r2++) {
                const int gr = rowA0 + wm + mt * 16 + ((lane >> 4) << 2) + r2;
                const int gc = rowB0 + wn + nt * 16 + (lane & 15);
                float v = acc[mt][nt][r2];
                if constexpr (EPI == 0) {
                    int m2 = gc / 384;
                    int rem = gc - m2 * 384;
                    int hh = rem >> 6, d = rem & 63;
                    if (m2 == 0) v *= 0.125f;  // q * headsize^-0.5
                    int bb = gr >> 8, t2 = gr & 255;
                    ((u16*)outp)[(size_t)m2 * QKV_ELEMS +
                                 ((size_t)((bb * 6 + hh) * 256 + t2) << 6) + d] = f2bf(v);
                } else if constexpr (EPI == 1) {
                    ((u16*)outp)[(size_t)gr * N + gc] =
                        f2bf(((const float*)resid)[(size_t)gr * N + gc] + bias[gc] + v);
                } else if constexpr (EPI == 2) {
                    float t2 = v + bias[gc];
                    ((u16*)outp)[(size_t)gr * N + gc] = f2bf(t2 > 0.f ? t2 : 0.f);
                } else {
                    ((float*)outp)[(size_t)gr * N + gc] =
                        bf2f(((const u16*)resid)[(size_t)gr * N + gc]) + bias[gc] + v;
                }
            }
        }
    }
}

// ---------- attention: one block per (b,h), 8 waves ----------
__global__ __launch_bounds__(512) void attn_kernel(
    const u16* __restrict__ q, const u16* __restrict__ k, const u16* __restrict__ v,
    u16* __restrict__ outp)
{
    __shared__ __align__(16) u16 Ks[256 * 64];
    __shared__ __align__(16) u16 Vt[64 * 256];
    __shared__ __align__(16) u16 Ps[8 * 512];   // per-wave P chunk [16 q][32 key]
    const int bh = blockIdx.x;
    const int tid = threadIdx.x, wave = tid >> 6, lane = tid & 63;
    const u16* qb = q + (size_t)bh * 16384;
    const u16* kb = k + (size_t)bh * 16384;
    const u16* vb = v + (size_t)bh * 16384;

    #pragma unroll
    for (int p = 0; p < 4; p++) {
        const int idx = p * 8 + wave;
        const int r = idx * 8 + (lane >> 3);
        const int csrc = (((lane & 7) ^ (r & 7)) << 3);
        gload_lds16(kb + (size_t)r * 64 + csrc, &Ks[idx * 512]);
    }
    #pragma unroll
    for (int p = 0; p < 4; p++) {
        const int e = (p * 512 + tid) * 8;
        const int key = e >> 6, d0 = e & 63;
        u16x8 raw = *(const u16x8*)(vb + (size_t)key * 64 + d0);
        #pragma unroll
        for (int j = 0; j < 8; j++) {
            const int d = d0 + j;
            Vt[d * 256 + (((key >> 3) ^ (d & 7)) << 3) + (key & 7)] = raw[j];
        }
    }
    __syncthreads();

    const int bI = bh / 6, hh = bh - bI * 6;

    #pragma unroll
    for (int t = 0; t < 2; t++) {
        const int qtile = (t == 0) ? wave : (15 - wave);
        const int qrowbase = qtile * 16;
        bfrag qf[2];
        {
            const int r = qrowbase + (lane & 15);
            qf[0] = *(const bfrag*)(qb + (size_t)r * 64 + ((lane >> 4) << 3));
            qf[1] = *(const bfrag*)(qb + (size_t)r * 64 + 32 + ((lane >> 4) << 3));
        }
        f32x4 S[16];
        #pragma unroll
        for (int kt = 0; kt < 16; kt++) {
            if (kt <= qtile) {
                f32x4 s = {0.f, 0.f, 0.f, 0.f};
                const int key = kt * 16 + (lane & 15);
                const char* kbase = (const char*)Ks + key * 128;
                s = mfma16(qf[0], *(const bfrag*)(kbase + ((((lane >> 4)) ^ (key & 7)) << 4)), s);
                s = mfma16(qf[1], *(const bfrag*)(kbase + (((4 + (lane >> 4)) ^ (key & 7)) << 4)), s);
                if (kt == qtile) {
                    const int qit = (lane >> 4) << 2;
                    #pragma unroll
                    for (int r2 = 0; r2 < 4; r2++)
                        if ((lane & 15) > qit + r2) s[r2] = -1e30f;
                }
                S[kt] = s;
            }
        }
        float mx[4] = {-1e30f, -1e30f, -1e30f, -1e30f};
        #pragma unroll
        for (int kt = 0; kt < 16; kt++) if (kt <= qtile)
            #pragma unroll
            for (int r2 = 0; r2 < 4; r2++) mx[r2] = fmaxf(mx[r2], S[kt][r2]);
        #pragma unroll
        for (int r2 = 0; r2 < 4; r2++) mx[r2] = redmax16(mx[r2]);
        float sm[4] = {0.f, 0.f, 0.f, 0.f};
        #pragma unroll
        for (int kt = 0; kt < 16; kt++) if (kt <= qtile)
            #pragma unroll
            for (int r2 = 0; r2 < 4; r2++) {
                float p = __expf(S[kt][r2] - mx[r2]);
                S[kt][r2] = p; sm[r2] += p;
            }
        #pragma unroll
        for (int r2 = 0; r2 < 4; r2++) sm[r2] = redsum16(sm[r2]);

        f32x4 O[4] = {};
        u16* Pw = &Ps[wave * 512];
        const int nch = (qtile + 2) >> 1;
        #pragma unroll
        for (int ch = 0; ch < 8; ch++) {
            if (ch < nch) {
                #pragma unroll
                for (int ktl = 0; ktl < 2; ktl++) {
                    const int kt = ch * 2 + ktl;
                    const int keyl = ktl * 16 + (lane & 15);
                    const int cidx = keyl >> 3;
                    #pragma unroll
                    for (int r2 = 0; r2 < 4; r2++) {
                        const int qq = ((lane >> 4) << 2) + r2;
                        float pv = (kt <= qtile) ? S[kt][r2] : 0.f;
                        Pw[qq * 32 + ((cidx ^ (qq & 3)) << 3) + (keyl & 7)] = f2bf(pv);
                    }
                }
                const int qq = lane & 15;
                bfrag pa = *(const bfrag*)(Pw + qq * 32 + (((lane >> 4) ^ (qq & 3)) << 3));
                #pragma unroll
                for (int dt = 0; dt < 4; dt++) {
                    const int d = dt * 16 + (lane & 15);
                    const int cc = ch * 4 + (lane >> 4);
                    bfrag vf = *(const bfrag*)((const char*)Vt + d * 512 + ((cc ^ (d & 7)) << 4));
                    O[dt] = mfma16(pa, vf, O[dt]);
                }
            }
        }
        #pragma unroll
        for (int dt = 0; dt < 4; dt++) {
            #pragma unroll
            for (int r2 = 0; r2 < 4; r2++) {
                const int qg = qrowbase + ((lane >> 4) << 2) + r2;
                const float val = O[dt][r2] / sm[r2];
                outp[(size_t)(bI * 256 + qg) * 384 + hh * 64 + dt * 16 + (lane & 15)] = f2bf(val);
            }
        }
    }
}

// ---------- launch ----------
extern "C" void kernel_launch(void* const* d_in, const int* in_sizes, int n_in,
                              void* d_out, int out_size, void* d_ws, size_t ws_size,
                              hipStream_t stream)
{
    const float* x    = (const float*)d_in[0];
    const float* ln1g = (const float*)d_in[1];
    const float* ln1b = (const float*)d_in[2];
    const float* Wq   = (const float*)d_in[3];
    const float* Wk   = (const float*)d_in[4];
    const float* Wv   = (const float*)d_in[5];
    const float* Wo   = (const float*)d_in[6];
    const float* bo   = (const float*)d_in[7];
    const float* ln2g = (const float*)d_in[8];
    const float* ln2b = (const float*)d_in[9];
    const float* W1   = (const float*)d_in[10];
    const float* b1   = (const float*)d_in[11];
    const float* W2   = (const float*)d_in[12];
    const float* b2   = (const float*)d_in[13];

    if (ws_size < 230031360u) return;

    char* ws = (char*)d_ws;
    u16*   wqkvT = (u16*)(ws + 0);
    u16*   woT   = (u16*)(ws + 884736);
    u16*   w1T   = (u16*)(ws + 1179648);
    u16*   w2T   = (u16*)(ws + 2359296);
    u16*   hbuf  = (u16*)(ws + 3538944);    // LN1 out, later attn out
    u16*   qbuf  = (u16*)(ws + 28704768);   // q, later h2 (LN2 out)
    u16*   kbuf  = (u16*)(ws + 53870592);
    u16*   vbuf  = (u16*)(ws + 79036416);
    u16*   x2h   = (u16*)(ws + 104202240);  // bf16 residual stream
    u16*   mid   = (u16*)(ws + 129368064);  // FFN hidden (bf16)
    float* out   = (float*)d_out;

    prep_weights<<<432, 256, 0, stream>>>(Wq, Wk, Wv, Wo, W1, W2, wqkvT, woT, w1T, w2T);
    ln_f32<<<8192, 256, 0, stream>>>(x, ln1g, ln1b, hbuf);
    gemm_pipe<0, 6><<<2304, 512, 0, stream>>>(hbuf, wqkvT, nullptr, nullptr, qbuf,
                                              NTOK, 1152);
    attn_kernel<<<768, 512, 0, stream>>>(qbuf, kbuf, vbuf, hbuf);
    gemm_pipe<1, 6><<<768, 512, 0, stream>>>(hbuf, woT, bo, x, x2h, NTOK, 384);
    ln_bf16<<<8192, 256, 0, stream>>>(x2h, ln2g, ln2b, qbuf);
    gemm_pipe<2, 6><<<3072, 512, 0, stream>>>(qbuf, w1T, b1, nullptr, mid, NTOK, 1536);
    gemm_pipe<3, 24><<<768, 512, 0, stream>>>(mid, w2T, b2, x2h, out, NTOK, 384);
}

// Round 5
// 230.238 us; speedup vs baseline: 1.6320x; 1.0725x over previous
//
#include <hip/hip_runtime.h>

typedef unsigned int u32;
typedef unsigned short u16;
typedef __bf16 bf16_t;
typedef float f32x4 __attribute__((ext_vector_type(4)));
typedef bf16_t bfrag __attribute__((ext_vector_type(8)));
typedef u16 u16x8 __attribute__((ext_vector_type(8)));

// ---------- helpers ----------
__device__ inline u16 f2bf(float f) {
    union { float f; u32 u; } v; v.f = f;
    u32 r = v.u + 0x7fffu + ((v.u >> 16) & 1u);   // RNE
    return (u16)(r >> 16);
}
__device__ inline float bf2f(u16 h) {
    union { u32 u; float f; } v; v.u = ((u32)h) << 16; return v.f;
}

__device__ inline f32x4 mfma16(bfrag a, bfrag b, f32x4 c) {
    return __builtin_amdgcn_mfma_f32_16x16x32_bf16(a, b, c, 0, 0, 0);
}

__device__ inline void gload_lds16(const void* g, void* l) {
    __builtin_amdgcn_global_load_lds((const __attribute__((address_space(1))) u32*)g,
                                     (__attribute__((address_space(3))) u32*)l, 16, 0, 0);
}

__device__ inline float redmax16(float v) {
    #pragma unroll
    for (int m = 1; m < 16; m <<= 1) v = fmaxf(v, __shfl_xor(v, m));
    return v;
}
__device__ inline float redsum16(float v) {
    #pragma unroll
    for (int m = 1; m < 16; m <<= 1) v += __shfl_xor(v, m);
    return v;
}

// ---------- sizes (fixed problem) ----------
// B=128 T=256 C=384 H=6 D=64; tokens M=32768
#define NTOK 32768
#define QKV_ELEMS 12582912   // 128*6*256*64

// ---------- weight prep: tiled 64x64 transpose fp32->bf16 ----------
__global__ __launch_bounds__(256) void prep_weights(
    const float* __restrict__ Wq, const float* __restrict__ Wk,
    const float* __restrict__ Wv, const float* __restrict__ Wo,
    const float* __restrict__ W1, const float* __restrict__ W2,
    u16* __restrict__ wqkvT, u16* __restrict__ woT,
    u16* __restrict__ w1T, u16* __restrict__ w2T)
{
    __shared__ float tile[64][65];
    const int b = blockIdx.x;
    const float* src; u16* dst;
    int sr0, sc0, srs, dr0, dc0, drs;
    if (b < 36) {                       // Wo [384][384] -> woT [384][384]
        int i = b / 6, j = b - i * 6;
        src = Wo;  srs = 384;  sr0 = i * 64; sc0 = j * 64;
        dst = woT; drs = 384;  dr0 = j * 64; dc0 = i * 64;
    } else if (b < 180) {               // W1 [384][1536] -> w1T [1536][384]
        int t = b - 36; int i = t / 24, j = t - i * 24;
        src = W1;  srs = 1536; sr0 = i * 64; sc0 = j * 64;
        dst = w1T; drs = 384;  dr0 = j * 64; dc0 = i * 64;
    } else if (b < 324) {               // W2 [1536][384] -> w2T [384][1536]
        int t = b - 180; int i = t / 6, j = t - i * 6;
        src = W2;  srs = 384;  sr0 = i * 64; sc0 = j * 64;
        dst = w2T; drs = 1536; dr0 = j * 64; dc0 = i * 64;
    } else {                            // W{q,k,v} [6][384][64] -> wqkvT [1152][384]
        int t = b - 324;
        int m2 = t / 36; t -= m2 * 36;
        int h = t / 6, tt = t - h * 6;
        src = (m2 == 0) ? Wq : ((m2 == 1) ? Wk : Wv);
        srs = 64;  sr0 = h * 384 + tt * 64; sc0 = 0;
        dst = wqkvT; drs = 384; dr0 = m2 * 384 + h * 64; dc0 = tt * 64;
    }
    const int lane = threadIdx.x & 63, grp = threadIdx.x >> 6;
    #pragma unroll
    for (int i = 0; i < 16; i++) {
        int r = grp * 16 + i;
        tile[r][lane] = src[(size_t)(sr0 + r) * srs + sc0 + lane];
    }
    __syncthreads();
    #pragma unroll
    for (int i = 0; i < 16; i++) {
        int r = grp * 16 + i;
        dst[(size_t)(dr0 + r) * drs + dc0 + lane] = f2bf(tile[lane][r]);
    }
}

// ---------- layernorm fp32-in ----------
__global__ __launch_bounds__(256) void ln_f32(
    const float* __restrict__ x, const float* __restrict__ g,
    const float* __restrict__ b, u16* __restrict__ out)
{
    const int row = blockIdx.x * 4 + (threadIdx.x >> 6);
    const int lane = threadIdx.x & 63;
    const float2* xr = (const float2*)(x + (size_t)row * 384);
    float2 v[3];
    float s = 0.f, s2 = 0.f;
    #pragma unroll
    for (int i = 0; i < 3; i++) {
        v[i] = xr[lane + i * 64];
        s += v[i].x + v[i].y; s2 += v[i].x * v[i].x + v[i].y * v[i].y;
    }
    #pragma unroll
    for (int m = 1; m < 64; m <<= 1) { s += __shfl_xor(s, m); s2 += __shfl_xor(s2, m); }
    float mean = s * (1.f / 384.f);
    float rstd = rsqrtf(s2 * (1.f / 384.f) - mean * mean + 1e-5f);
    u32* op = (u32*)(out + (size_t)row * 384);
    #pragma unroll
    for (int i = 0; i < 3; i++) {
        int c = (lane + i * 64) * 2;
        u32 lo = f2bf((v[i].x - mean) * rstd * g[c] + b[c]);
        u32 hi = f2bf((v[i].y - mean) * rstd * g[c + 1] + b[c + 1]);
        op[lane + i * 64] = lo | (hi << 16);
    }
}

// ---------- layernorm bf16-in ----------
__global__ __launch_bounds__(256) void ln_bf16(
    const u16* __restrict__ x, const float* __restrict__ g,
    const float* __restrict__ b, u16* __restrict__ out)
{
    const int row = blockIdx.x * 4 + (threadIdx.x >> 6);
    const int lane = threadIdx.x & 63;
    const u32* xr = (const u32*)(x + (size_t)row * 384);
    float vx[3], vy[3];
    float s = 0.f, s2 = 0.f;
    #pragma unroll
    for (int i = 0; i < 3; i++) {
        u32 w = xr[lane + i * 64];
        vx[i] = bf2f((u16)(w & 0xffffu));
        vy[i] = bf2f((u16)(w >> 16));
        s += vx[i] + vy[i]; s2 += vx[i] * vx[i] + vy[i] * vy[i];
    }
    #pragma unroll
    for (int m = 1; m < 64; m <<= 1) { s += __shfl_xor(s, m); s2 += __shfl_xor(s2, m); }
    float mean = s * (1.f / 384.f);
    float rstd = rsqrtf(s2 * (1.f / 384.f) - mean * mean + 1e-5f);
    u32* op = (u32*)(out + (size_t)row * 384);
    #pragma unroll
    for (int i = 0; i < 3; i++) {
        int c = (lane + i * 64) * 2;
        u32 lo = f2bf((vx[i] - mean) * rstd * g[c] + b[c]);
        u32 hi = f2bf((vy[i] - mean) * rstd * g[c + 1] + b[c + 1]);
        op[lane + i * 64] = lo | (hi << 16);
    }
}

// ---------- m97-structure GEMM: A[M,K] x Bt[N,K], 128x128 tile, BK=64 ----------
// 4 waves, 64x64 wave tiles, acc[4][4], SINGLE 32 KB LDS buffer, 2 barriers/step.
// Latency hidden by 4 blocks/CU (16 waves/CU) TLP, not by explicit pipelining.
// EPI 0: qkv scatter (bf16, q scaled)  EPI 1: bf16 out = f32resid + bias + acc
// EPI 2: bf16 out = relu(acc + bias)   EPI 3: f32 out = bf16resid + bias + acc
template<int EPI, int NT>
__global__ __launch_bounds__(256, 4) void gemm_m97(
    const u16* __restrict__ A, const u16* __restrict__ Bt,
    const float* __restrict__ bias, const void* __restrict__ resid,
    void* __restrict__ outp, int M, int N)
{
    const int K = NT * 64;
    __shared__ __align__(16) u16 As[128 * 64];
    __shared__ __align__(16) u16 Bs[128 * 64];
    const int tid = threadIdx.x, wave = tid >> 6, lane = tid & 63;
    const int nbn = N >> 7;
    const int nwg = gridDim.x;
    const int bid = blockIdx.x;
    const int wg = (bid & 7) * (nwg >> 3) + (bid >> 3);   // XCD-chunked swizzle
    const int bm = wg / nbn, bn = wg - bm * nbn;          // bn fastest: A reuse in-XCD
    const int rowA0 = bm << 7, rowB0 = bn << 7;
    const int wm = (wave >> 1) << 6, wn = (wave & 1) << 6;
    const int lr = lane >> 3, lc = lane & 7;
    f32x4 acc[4][4] = {};

    for (int t = 0; t < NT; ++t) {
        const int ko = t << 6;
        #pragma unroll
        for (int p = 0; p < 4; p++) {
            const int idx = p * 4 + wave;
            const int r = idx * 8 + lr;
            const int csrc = ((lc ^ (r & 7)) << 3);
            gload_lds16(A + (size_t)(rowA0 + r) * K + ko + csrc, &As[idx * 512]);
            gload_lds16(Bt + (size_t)(rowB0 + r) * K + ko + csrc, &Bs[idx * 512]);
        }
        __syncthreads();
        #pragma unroll
        for (int kk = 0; kk < 2; kk++) {
            bfrag af[4], bfr[4];
            #pragma unroll
            for (int mt = 0; mt < 4; mt++) {
                const int row = wm + mt * 16 + (lane & 15);
                af[mt] = *(const bfrag*)((const char*)As + row * 128 +
                          (((kk * 4 + (lane >> 4)) ^ (row & 7)) << 4));
            }
            #pragma unroll
            for (int nt = 0; nt < 4; nt++) {
                const int row = wn + nt * 16 + (lane & 15);
                bfr[nt] = *(const bfrag*)((const char*)Bs + row * 128 +
                          (((kk * 4 + (lane >> 4)) ^ (row & 7)) << 4));
            }
            #pragma unroll
            for (int mt = 0; mt < 4; mt++)
                #pragma unroll
                for (int nt = 0; nt < 4; nt++)
                    acc[mt][nt] = mfma16(af[mt], bfr[nt], acc[mt][nt]);
        }
        __syncthreads();
    }

    #pragma unroll
    for (int mt = 0; mt < 4; mt++) {
        #pragma unroll
        for (int nt = 0; nt < 4; nt++) {
            #pragma unroll
            for (int r2 = 0; r2 < 4; r2++) {
                const int gr = rowA0 + wm + mt * 16 + ((lane >> 4) << 2) + r2;
                const int gc = rowB0 + wn + nt * 16 + (lane & 15);
                float v = acc[mt][nt][r2];
                if constexpr (EPI == 0) {
                    int m2 = gc / 384;
                    int rem = gc - m2 * 384;
                    int hh = rem >> 6, d = rem & 63;
                    if (m2 == 0) v *= 0.125f;  // q * headsize^-0.5
                    int bb = gr >> 8, t2 = gr & 255;
                    ((u16*)outp)[(size_t)m2 * QKV_ELEMS +
                                 ((size_t)((bb * 6 + hh) * 256 + t2) << 6) + d] = f2bf(v);
                } else if constexpr (EPI == 1) {
                    ((u16*)outp)[(size_t)gr * N + gc] =
                        f2bf(((const float*)resid)[(size_t)gr * N + gc] + bias[gc] + v);
                } else if constexpr (EPI == 2) {
                    float t2 = v + bias[gc];
                    ((u16*)outp)[(size_t)gr * N + gc] = f2bf(t2 > 0.f ? t2 : 0.f);
                } else {
                    ((float*)outp)[(size_t)gr * N + gc] =
                        bf2f(((const u16*)resid)[(size_t)gr * N + gc]) + bias[gc] + v;
                }
            }
        }
    }
}

// ---------- attention: one block per (b,h), 8 waves ----------
__global__ __launch_bounds__(512) void attn_kernel(
    const u16* __restrict__ q, const u16* __restrict__ k, const u16* __restrict__ v,
    u16* __restrict__ outp)
{
    __shared__ __align__(16) u16 Ks[256 * 64];
    __shared__ __align__(16) u16 Vt[64 * 256];
    __shared__ __align__(16) u16 Ps[8 * 512];   // per-wave P chunk [16 q][32 key]
    const int bh = blockIdx.x;
    const int tid = threadIdx.x, wave = tid >> 6, lane = tid & 63;
    const u16* qb = q + (size_t)bh * 16384;
    const u16* kb = k + (size_t)bh * 16384;
    const u16* vb = v + (size_t)bh * 16384;

    #pragma unroll
    for (int p = 0; p < 4; p++) {
        const int idx = p * 8 + wave;
        const int r = idx * 8 + (lane >> 3);
        const int csrc = (((lane & 7) ^ (r & 7)) << 3);
        gload_lds16(kb + (size_t)r * 64 + csrc, &Ks[idx * 512]);
    }
    #pragma unroll
    for (int p = 0; p < 4; p++) {
        const int e = (p * 512 + tid) * 8;
        const int key = e >> 6, d0 = e & 63;
        u16x8 raw = *(const u16x8*)(vb + (size_t)key * 64 + d0);
        #pragma unroll
        for (int j = 0; j < 8; j++) {
            const int d = d0 + j;
            Vt[d * 256 + (((key >> 3) ^ (d & 7)) << 3) + (key & 7)] = raw[j];
        }
    }
    __syncthreads();

    const int bI = bh / 6, hh = bh - bI * 6;

    #pragma unroll
    for (int t = 0; t < 2; t++) {
        const int qtile = (t == 0) ? wave : (15 - wave);
        const int qrowbase = qtile * 16;
        bfrag qf[2];
        {
            const int r = qrowbase + (lane & 15);
            qf[0] = *(const bfrag*)(qb + (size_t)r * 64 + ((lane >> 4) << 3));
            qf[1] = *(const bfrag*)(qb + (size_t)r * 64 + 32 + ((lane >> 4) << 3));
        }
        f32x4 S[16];
        #pragma unroll
        for (int kt = 0; kt < 16; kt++) {
            if (kt <= qtile) {
                f32x4 s = {0.f, 0.f, 0.f, 0.f};
                const int key = kt * 16 + (lane & 15);
                const char* kbase = (const char*)Ks + key * 128;
                s = mfma16(qf[0], *(const bfrag*)(kbase + ((((lane >> 4)) ^ (key & 7)) << 4)), s);
                s = mfma16(qf[1], *(const bfrag*)(kbase + (((4 + (lane >> 4)) ^ (key & 7)) << 4)), s);
                if (kt == qtile) {
                    const int qit = (lane >> 4) << 2;
                    #pragma unroll
                    for (int r2 = 0; r2 < 4; r2++)
                        if ((lane & 15) > qit + r2) s[r2] = -1e30f;
                }
                S[kt] = s;
            }
        }
        float mx[4] = {-1e30f, -1e30f, -1e30f, -1e30f};
        #pragma unroll
        for (int kt = 0; kt < 16; kt++) if (kt <= qtile)
            #pragma unroll
            for (int r2 = 0; r2 < 4; r2++) mx[r2] = fmaxf(mx[r2], S[kt][r2]);
        #pragma unroll
        for (int r2 = 0; r2 < 4; r2++) mx[r2] = redmax16(mx[r2]);
        float sm[4] = {0.f, 0.f, 0.f, 0.f};
        #pragma unroll
        for (int kt = 0; kt < 16; kt++) if (kt <= qtile)
            #pragma unroll
            for (int r2 = 0; r2 < 4; r2++) {
                float p = __expf(S[kt][r2] - mx[r2]);
                S[kt][r2] = p; sm[r2] += p;
            }
        #pragma unroll
        for (int r2 = 0; r2 < 4; r2++) sm[r2] = redsum16(sm[r2]);

        f32x4 O[4] = {};
        u16* Pw = &Ps[wave * 512];
        const int nch = (qtile + 2) >> 1;
        #pragma unroll
        for (int ch = 0; ch < 8; ch++) {
            if (ch < nch) {
                #pragma unroll
                for (int ktl = 0; ktl < 2; ktl++) {
                    const int kt = ch * 2 + ktl;
                    const int keyl = ktl * 16 + (lane & 15);
                    const int cidx = keyl >> 3;
                    #pragma unroll
                    for (int r2 = 0; r2 < 4; r2++) {
                        const int qq = ((lane >> 4) << 2) + r2;
                        float pv = (kt <= qtile) ? S[kt][r2] : 0.f;
                        Pw[qq * 32 + ((cidx ^ (qq & 3)) << 3) + (keyl & 7)] = f2bf(pv);
                    }
                }
                const int qq = lane & 15;
                bfrag pa = *(const bfrag*)(Pw + qq * 32 + (((lane >> 4) ^ (qq & 3)) << 3));
                #pragma unroll
                for (int dt = 0; dt < 4; dt++) {
                    const int d = dt * 16 + (lane & 15);
                    const int cc = ch * 4 + (lane >> 4);
                    bfrag vf = *(const bfrag*)((const char*)Vt + d * 512 + ((cc ^ (d & 7)) << 4));
                    O[dt] = mfma16(pa, vf, O[dt]);
                }
            }
        }
        #pragma unroll
        for (int dt = 0; dt < 4; dt++) {
            #pragma unroll
            for (int r2 = 0; r2 < 4; r2++) {
                const int qg = qrowbase + ((lane >> 4) << 2) + r2;
                const float val = O[dt][r2] / sm[r2];
                outp[(size_t)(bI * 256 + qg) * 384 + hh * 64 + dt * 16 + (lane & 15)] = f2bf(val);
            }
        }
    }
}

// ---------- launch ----------
extern "C" void kernel_launch(void* const* d_in, const int* in_sizes, int n_in,
                              void* d_out, int out_size, void* d_ws, size_t ws_size,
                              hipStream_t stream)
{
    const float* x    = (const float*)d_in[0];
    const float* ln1g = (const float*)d_in[1];
    const float* ln1b = (const float*)d_in[2];
    const float* Wq   = (const float*)d_in[3];
    const float* Wk   = (const float*)d_in[4];
    const float* Wv   = (const float*)d_in[5];
    const float* Wo   = (const float*)d_in[6];
    const float* bo   = (const float*)d_in[7];
    const float* ln2g = (const float*)d_in[8];
    const float* ln2b = (const float*)d_in[9];
    const float* W1   = (const float*)d_in[10];
    const float* b1   = (const float*)d_in[11];
    const float* W2   = (const float*)d_in[12];
    const float* b2   = (const float*)d_in[13];

    if (ws_size < 230031360u) return;

    char* ws = (char*)d_ws;
    u16*   wqkvT = (u16*)(ws + 0);
    u16*   woT   = (u16*)(ws + 884736);
    u16*   w1T   = (u16*)(ws + 1179648);
    u16*   w2T   = (u16*)(ws + 2359296);
    u16*   hbuf  = (u16*)(ws + 3538944);    // LN1 out, later attn out
    u16*   qbuf  = (u16*)(ws + 28704768);   // q, later h2 (LN2 out)
    u16*   kbuf  = (u16*)(ws + 53870592);
    u16*   vbuf  = (u16*)(ws + 79036416);
    u16*   x2h   = (u16*)(ws + 104202240);  // bf16 residual stream
    u16*   mid   = (u16*)(ws + 129368064);  // FFN hidden (bf16)
    float* out   = (float*)d_out;

    prep_weights<<<432, 256, 0, stream>>>(Wq, Wk, Wv, Wo, W1, W2, wqkvT, woT, w1T, w2T);
    ln_f32<<<8192, 256, 0, stream>>>(x, ln1g, ln1b, hbuf);
    gemm_m97<0, 6><<<2304, 256, 0, stream>>>(hbuf, wqkvT, nullptr, nullptr, qbuf,
                                             NTOK, 1152);
    attn_kernel<<<768, 512, 0, stream>>>(qbuf, kbuf, vbuf, hbuf);
    gemm_m97<1, 6><<<768, 256, 0, stream>>>(hbuf, woT, bo, x, x2h, NTOK, 384);
    ln_bf16<<<8192, 256, 0, stream>>>(x2h, ln2g, ln2b, qbuf);
    gemm_m97<2, 6><<<3072, 256, 0, stream>>>(qbuf, w1T, b1, nullptr, mid, NTOK, 1536);
    gemm_m97<3, 24><<<768, 256, 0, stream>>>(mid, w2T, b2, x2h, out, NTOK, 384);
}